// Round 1
// baseline (170.429 us; speedup 1.0000x reference)
//
#include <hip/hip_runtime.h>

#define NN 32768
#define MM 4096
#define DD 32

// ---------------------------------------------------------------------------
// Pre-kernel: w[j] = alpha[j] * exp(-0.5 * ||y_j||^2 / g^2)
// ---------------------------------------------------------------------------
__global__ __launch_bounds__(256) void wkern(const float* __restrict__ C,
                                             const float* __restrict__ alphas,
                                             const float* __restrict__ sigma,
                                             float* __restrict__ w) {
    int j = blockIdx.x * 256 + threadIdx.x;
    if (j >= MM) return;
    float g = sigma[0];
    float inv_g2 = 1.0f / (g * g);
    const float4* cp = (const float4*)(C + (size_t)j * DD);
    float y2 = 0.f;
#pragma unroll
    for (int q = 0; q < DD / 4; ++q) {
        float4 v = cp[q];
        y2 = fmaf(v.x, v.x, y2);
        y2 = fmaf(v.y, v.y, y2);
        y2 = fmaf(v.z, v.z, y2);
        y2 = fmaf(v.w, v.w, y2);
    }
    const float LOG2E = 1.44269504088896340736f;
    w[j] = alphas[j] * exp2f(-0.5f * inv_g2 * LOG2E * y2);
}

// ---------------------------------------------------------------------------
// Main kernel: each thread owns one row of X (32 floats in VGPRs).
// j is wave-uniform -> centers are fetched via scalar loads (s_load) and the
// inner product is v_fmac_f32 v, s, v. blockIdx.y splits M into SPLIT slices;
// partial sums land in ws, reduced by reduce_kern.
// out-of-exp folding: out_i = sum_j w_j * exp2(A*dot + B_i)
//   A = log2(e)/g^2, B_i = -0.5*A*||x_i||^2, w_j = alpha_j*exp(-0.5*||y_j||^2/g^2)
// ---------------------------------------------------------------------------
template <int SPLIT>
__global__ __launch_bounds__(128) void rbf_partial(const float* __restrict__ X,
                                                   const float* __restrict__ C,
                                                   const float* __restrict__ w,
                                                   const float* __restrict__ sigma,
                                                   float* __restrict__ part) {
    const int row = blockIdx.x * 128 + threadIdx.x;
    const int slice = blockIdx.y;

    const float g = sigma[0];
    const float inv_g2 = 1.0f / (g * g);
    const float A = inv_g2 * 1.44269504088896340736f;

    // Load this thread's x row into registers (fully unrolled -> VGPRs).
    float x[DD];
    const float4* xp = (const float4*)(X + (size_t)row * DD);
#pragma unroll
    for (int q = 0; q < DD / 4; ++q) {
        float4 v = xp[q];
        x[4 * q + 0] = v.x;
        x[4 * q + 1] = v.y;
        x[4 * q + 2] = v.z;
        x[4 * q + 3] = v.w;
    }
    float x2 = 0.f;
#pragma unroll
    for (int d = 0; d < DD; ++d) x2 = fmaf(x[d], x[d], x2);
    const float B = -0.5f * A * x2;

    constexpr int MPER = MM / SPLIT;
    const int j0 = slice * MPER;
    const float* cp = C + (size_t)j0 * DD;
    const float* wp = w + j0;

    float acc = 0.f;
#pragma unroll 2
    for (int j = 0; j < MPER; ++j) {
        const float* cj = cp + j * DD;  // uniform address -> s_load
        float d0 = 0.f, d1 = 0.f, d2 = 0.f, d3 = 0.f;
#pragma unroll
        for (int d = 0; d < DD; d += 4) {
            d0 = fmaf(cj[d + 0], x[d + 0], d0);
            d1 = fmaf(cj[d + 1], x[d + 1], d1);
            d2 = fmaf(cj[d + 2], x[d + 2], d2);
            d3 = fmaf(cj[d + 3], x[d + 3], d3);
        }
        float dot = (d0 + d1) + (d2 + d3);
        float e = exp2f(fmaf(dot, A, B));
        acc = fmaf(wp[j], e, acc);
    }
    part[(size_t)slice * NN + row] = acc;
}

// ---------------------------------------------------------------------------
// Reduction over the SPLIT partial slabs.
// ---------------------------------------------------------------------------
template <int SPLIT>
__global__ __launch_bounds__(256) void reduce_kern(const float* __restrict__ part,
                                                   float* __restrict__ out) {
    int i = blockIdx.x * 256 + threadIdx.x;
    float s = 0.f;
#pragma unroll
    for (int k = 0; k < SPLIT; ++k) s += part[(size_t)k * NN + i];
    out[i] = s;
}

extern "C" void kernel_launch(void* const* d_in, const int* in_sizes, int n_in,
                              void* d_out, int out_size, void* d_ws, size_t ws_size,
                              hipStream_t stream) {
    const float* X  = (const float*)d_in[0];
    const float* C  = (const float*)d_in[1];
    const float* al = (const float*)d_in[2];
    const float* sg = (const float*)d_in[3];
    float* out = (float*)d_out;

    float* w    = (float*)d_ws;
    float* part = (float*)((char*)d_ws + MM * sizeof(float));

    constexpr int SPLIT = 8;
    const size_t need = MM * sizeof(float) + (size_t)SPLIT * NN * sizeof(float);

    wkern<<<MM / 256, 256, 0, stream>>>(C, al, sg, w);

    if (ws_size >= need) {
        dim3 grid(NN / 128, SPLIT);
        rbf_partial<SPLIT><<<grid, 128, 0, stream>>>(X, C, w, sg, part);
        reduce_kern<SPLIT><<<NN / 256, 256, 0, stream>>>(part, out);
    } else {
        // Fallback: no M-split (needs only the 16 KB w buffer).
        dim3 grid(NN / 128, 1);
        rbf_partial<1><<<grid, 128, 0, stream>>>(X, C, w, sg, out);
    }
}

// Round 2
// 56.708 us; speedup vs baseline: 3.0054x; 3.0054x over previous
//
#include <hip/hip_runtime.h>

#define NN 32768
#define MM 4096
#define DD 32

typedef short short8 __attribute__((ext_vector_type(8)));
typedef float f32x4 __attribute__((ext_vector_type(4)));

#define MSPLIT 8       // M-dimension split (grid.y)
#define ROWTILES 4     // 16-row MFMA tiles per wave -> 64 rows/wave
#define WAVES 4        // waves per block -> 256 rows/block

__device__ __forceinline__ unsigned short f2bf(float f) {
    unsigned u = __float_as_uint(f);
    unsigned r = 0x7FFFu + ((u >> 16) & 1u);
    return (unsigned short)((u + r) >> 16);
}
__device__ __forceinline__ float bf2f(unsigned short h) {
    return __uint_as_float(((unsigned)h) << 16);
}

// ---------------------------------------------------------------------------
// Prep: split X and C into bf16 hi/lo pairs; Bx_i = -0.5*LA*||x_i||^2 ;
// w_j = alpha_j * 2^(-0.5*LA*||y_j||^2),  LA = log2(e)/g^2.
// ---------------------------------------------------------------------------
__global__ __launch_bounds__(256) void prep_kern(
    const float* __restrict__ X, const float* __restrict__ C,
    const float* __restrict__ alphas, const float* __restrict__ sigma,
    unsigned short* __restrict__ Xh, unsigned short* __restrict__ Xl,
    unsigned short* __restrict__ Ch, unsigned short* __restrict__ Cl,
    float* __restrict__ Bx, float* __restrict__ w)
{
    int i = blockIdx.x * 256 + threadIdx.x;
    float g = sigma[0];
    float LA = 1.44269504088896340736f / (g * g);

    const float* src;
    unsigned short* dh;
    unsigned short* dl;
    int row;
    bool isX = (i < NN);
    if (isX) {
        row = i;
        src = X + (size_t)row * DD;
        dh = Xh + (size_t)row * DD;
        dl = Xl + (size_t)row * DD;
    } else {
        row = i - NN;
        if (row >= MM) return;
        src = C + (size_t)row * DD;
        dh = Ch + (size_t)row * DD;
        dl = Cl + (size_t)row * DD;
    }

    float s2 = 0.f;
#pragma unroll
    for (int q = 0; q < DD / 8; ++q) {
        float4 a = ((const float4*)src)[2 * q];
        float4 b = ((const float4*)src)[2 * q + 1];
        float vv[8] = {a.x, a.y, a.z, a.w, b.x, b.y, b.z, b.w};
        short8 hv, lv;
#pragma unroll
        for (int e = 0; e < 8; ++e) {
            float v = vv[e];
            s2 = fmaf(v, v, s2);
            unsigned short h = f2bf(v);
            hv[e] = (short)h;
            lv[e] = (short)f2bf(v - bf2f(h));
        }
        ((short8*)dh)[q] = hv;
        ((short8*)dl)[q] = lv;
    }
    float b = -0.5f * LA * s2;
    if (isX) Bx[row] = b;
    else     w[row] = alphas[row] * exp2f(b);
}

// ---------------------------------------------------------------------------
// Main: double-bf16 MFMA GEMM fused with exp epilogue.
// Each wave: 4 row-tiles (64 rows), M/8 columns (32 col-tiles).
// dot = xh*yh + xh*yl + xl*yh via 3 chained mfma_f32_16x16x32_bf16.
// out partial += w_j * exp2(LA*dot + Bx_i); cross-lane reduce over cols.
// ---------------------------------------------------------------------------
__global__ __launch_bounds__(256) void rbf_mfma(
    const unsigned short* __restrict__ Xh, const unsigned short* __restrict__ Xl,
    const unsigned short* __restrict__ Ch, const unsigned short* __restrict__ Cl,
    const float* __restrict__ Bx, const float* __restrict__ w,
    const float* __restrict__ sigma, float* __restrict__ part)
{
    const int wave = threadIdx.x >> 6;
    const int lane = threadIdx.x & 63;
    const int l15 = lane & 15;
    const int lhi = lane >> 4;
    const int rowbase = (blockIdx.x * WAVES + wave) * (16 * ROWTILES);
    const int slice = blockIdx.y;

    const float g = sigma[0];
    const float LA = 1.44269504088896340736f / (g * g);

    // A fragments (hi/lo) for the 4 row-tiles: 8 contiguous bf16 per lane.
    short8 ah[ROWTILES], al[ROWTILES];
#pragma unroll
    for (int t = 0; t < ROWTILES; ++t) {
        int r = rowbase + t * 16 + l15;
        ah[t] = *(const short8*)(Xh + (size_t)r * DD + lhi * 8);
        al[t] = *(const short8*)(Xl + (size_t)r * DD + lhi * 8);
    }
    // Row exponent offsets (C/D frag: row = lhi*4 + r within the tile).
    float bx[ROWTILES][4];
#pragma unroll
    for (int t = 0; t < ROWTILES; ++t)
#pragma unroll
        for (int r = 0; r < 4; ++r)
            bx[t][r] = Bx[rowbase + t * 16 + lhi * 4 + r];

    float acc[ROWTILES][4];
#pragma unroll
    for (int t = 0; t < ROWTILES; ++t)
#pragma unroll
        for (int r = 0; r < 4; ++r) acc[t][r] = 0.f;

    constexpr int MPER = MM / MSPLIT;
    constexpr int NT = MPER / 16;
    const int j0 = slice * MPER;

    const unsigned short* chp = Ch + ((size_t)j0 + l15) * DD + lhi * 8;
    const unsigned short* clp = Cl + ((size_t)j0 + l15) * DD + lhi * 8;

    short8 bh = *(const short8*)chp;
    short8 bl = *(const short8*)clp;
    float wj = w[j0 + l15];

    for (int jt = 0; jt < NT; ++jt) {
        short8 nbh = bh, nbl = bl;
        float nwj = wj;
        if (jt + 1 < NT) {
            nbh = *(const short8*)(chp + (size_t)(jt + 1) * 16 * DD);
            nbl = *(const short8*)(clp + (size_t)(jt + 1) * 16 * DD);
            nwj = w[j0 + (jt + 1) * 16 + l15];
        }
#pragma unroll
        for (int t = 0; t < ROWTILES; ++t) {
            f32x4 d = {0.f, 0.f, 0.f, 0.f};
            d = __builtin_amdgcn_mfma_f32_16x16x32_bf16(ah[t], bl, d, 0, 0, 0);
            d = __builtin_amdgcn_mfma_f32_16x16x32_bf16(al[t], bh, d, 0, 0, 0);
            d = __builtin_amdgcn_mfma_f32_16x16x32_bf16(ah[t], bh, d, 0, 0, 0);
#pragma unroll
            for (int r = 0; r < 4; ++r) {
                float e = exp2f(fmaf(d[r], LA, bx[t][r]));
                acc[t][r] = fmaf(wj, e, acc[t][r]);
            }
        }
        bh = nbh; bl = nbl; wj = nwj;
    }

    // Reduce over the 16 columns each lane group holds (lane bits 0..3).
#pragma unroll
    for (int t = 0; t < ROWTILES; ++t)
#pragma unroll
        for (int r = 0; r < 4; ++r) {
            float v = acc[t][r];
            v += __shfl_xor(v, 1, 64);
            v += __shfl_xor(v, 2, 64);
            v += __shfl_xor(v, 4, 64);
            v += __shfl_xor(v, 8, 64);
            acc[t][r] = v;
        }
    if (l15 == 0) {
#pragma unroll
        for (int t = 0; t < ROWTILES; ++t)
#pragma unroll
            for (int r = 0; r < 4; ++r)
                part[(size_t)slice * NN + rowbase + t * 16 + lhi * 4 + r] = acc[t][r];
    }
}

__global__ __launch_bounds__(256) void reduce_kern8(const float* __restrict__ part,
                                                    float* __restrict__ out) {
    int i = blockIdx.x * 256 + threadIdx.x;
    float s = 0.f;
#pragma unroll
    for (int k = 0; k < MSPLIT; ++k) s += part[(size_t)k * NN + i];
    out[i] = s;
}

// ---------------------------------------------------------------------------
// Fallback (round-1 VALU path) in case ws_size is too small.
// ---------------------------------------------------------------------------
__global__ __launch_bounds__(256) void wkern(const float* __restrict__ C,
                                             const float* __restrict__ alphas,
                                             const float* __restrict__ sigma,
                                             float* __restrict__ w) {
    int j = blockIdx.x * 256 + threadIdx.x;
    if (j >= MM) return;
    float g = sigma[0];
    float inv_g2 = 1.0f / (g * g);
    const float4* cp = (const float4*)(C + (size_t)j * DD);
    float y2 = 0.f;
#pragma unroll
    for (int q = 0; q < DD / 4; ++q) {
        float4 v = cp[q];
        y2 = fmaf(v.x, v.x, y2);
        y2 = fmaf(v.y, v.y, y2);
        y2 = fmaf(v.z, v.z, y2);
        y2 = fmaf(v.w, v.w, y2);
    }
    w[j] = alphas[j] * exp2f(-0.5f * inv_g2 * 1.44269504088896340736f * y2);
}

__global__ __launch_bounds__(128) void rbf_valu(const float* __restrict__ X,
                                                const float* __restrict__ C,
                                                const float* __restrict__ w,
                                                const float* __restrict__ sigma,
                                                float* __restrict__ out) {
    const int row = blockIdx.x * 128 + threadIdx.x;
    const float g = sigma[0];
    const float A = 1.44269504088896340736f / (g * g);
    float x[DD];
    const float4* xp = (const float4*)(X + (size_t)row * DD);
#pragma unroll
    for (int q = 0; q < DD / 4; ++q) {
        float4 v = xp[q];
        x[4 * q + 0] = v.x; x[4 * q + 1] = v.y;
        x[4 * q + 2] = v.z; x[4 * q + 3] = v.w;
    }
    float x2 = 0.f;
#pragma unroll
    for (int d = 0; d < DD; ++d) x2 = fmaf(x[d], x[d], x2);
    const float B = -0.5f * A * x2;
    float acc = 0.f;
#pragma unroll 2
    for (int j = 0; j < MM; ++j) {
        const float* cj = C + (size_t)j * DD;
        float d0 = 0.f, d1 = 0.f, d2 = 0.f, d3 = 0.f;
#pragma unroll
        for (int d = 0; d < DD; d += 4) {
            d0 = fmaf(cj[d + 0], x[d + 0], d0);
            d1 = fmaf(cj[d + 1], x[d + 1], d1);
            d2 = fmaf(cj[d + 2], x[d + 2], d2);
            d3 = fmaf(cj[d + 3], x[d + 3], d3);
        }
        float dot = (d0 + d1) + (d2 + d3);
        acc = fmaf(w[j], exp2f(fmaf(dot, A, B)), acc);
    }
    out[row] = acc;
}

extern "C" void kernel_launch(void* const* d_in, const int* in_sizes, int n_in,
                              void* d_out, int out_size, void* d_ws, size_t ws_size,
                              hipStream_t stream) {
    const float* X  = (const float*)d_in[0];
    const float* C  = (const float*)d_in[1];
    const float* al = (const float*)d_in[2];
    const float* sg = (const float*)d_in[3];
    float* out = (float*)d_out;

    // Workspace layout (all 16B aligned).
    size_t off = 0;
    unsigned short* Xh = (unsigned short*)((char*)d_ws + off); off += (size_t)NN * DD * 2;
    unsigned short* Xl = (unsigned short*)((char*)d_ws + off); off += (size_t)NN * DD * 2;
    unsigned short* Ch = (unsigned short*)((char*)d_ws + off); off += (size_t)MM * DD * 2;
    unsigned short* Cl = (unsigned short*)((char*)d_ws + off); off += (size_t)MM * DD * 2;
    float* Bx = (float*)((char*)d_ws + off); off += (size_t)NN * 4;
    float* w  = (float*)((char*)d_ws + off); off += (size_t)MM * 4;
    float* part = (float*)((char*)d_ws + off); off += (size_t)MSPLIT * NN * 4;

    if (ws_size >= off) {
        prep_kern<<<(NN + MM) / 256, 256, 0, stream>>>(X, C, al, sg, Xh, Xl, Ch, Cl, Bx, w);
        dim3 grid(NN / (WAVES * 16 * ROWTILES), MSPLIT);
        rbf_mfma<<<grid, 64 * WAVES, 0, stream>>>(Xh, Xl, Ch, Cl, Bx, w, sg, part);
        reduce_kern8<<<NN / 256, 256, 0, stream>>>(part, out);
    } else {
        // Fallback: fp32 VALU path, needs only 16 KB for w.
        float* wf = (float*)d_ws;
        wkern<<<MM / 256, 256, 0, stream>>>(C, al, sg, wf);
        rbf_valu<<<NN / 128, 128, 0, stream>>>(X, C, wf, sg, out);
    }
}

// Round 3
// 40.014 us; speedup vs baseline: 4.2592x; 1.4172x over previous
//
#include <hip/hip_runtime.h>

#define NN 32768
#define MM 4096
#define DD 32

typedef short short8 __attribute__((ext_vector_type(8)));
typedef float f32x4 __attribute__((ext_vector_type(4)));

#define ROWTILES 4     // 16-row MFMA tiles per wave -> 64 rows/wave
#define WAVES 4        // waves per block -> 256 rows/block

__device__ __forceinline__ unsigned short f2bf(float f) {
    unsigned u = __float_as_uint(f);
    unsigned r = 0x7FFFu + ((u >> 16) & 1u);
    return (unsigned short)((u + r) >> 16);
}
__device__ __forceinline__ float bf2f(unsigned short h) {
    return __uint_as_float(((unsigned)h) << 16);
}

// ---------------------------------------------------------------------------
// Prep: X is PRE-SCALED by LA = log2(e)/g^2 before the bf16 hi/lo split, so
// the MFMA dot directly produces LA*(x.y). Bx_i = -0.5*LA*||x_i||^2 (raw x),
// w_j = alpha_j * 2^(-0.5*LA*||y_j||^2). C split is unscaled.
// ---------------------------------------------------------------------------
__global__ __launch_bounds__(256) void prep_kern(
    const float* __restrict__ X, const float* __restrict__ C,
    const float* __restrict__ alphas, const float* __restrict__ sigma,
    unsigned short* __restrict__ Xh, unsigned short* __restrict__ Xl,
    unsigned short* __restrict__ Ch, unsigned short* __restrict__ Cl,
    float* __restrict__ Bx, float* __restrict__ w)
{
    int i = blockIdx.x * 256 + threadIdx.x;
    float g = sigma[0];
    float LA = 1.44269504088896340736f / (g * g);

    const float* src;
    unsigned short* dh;
    unsigned short* dl;
    int row;
    bool isX = (i < NN);
    if (isX) {
        row = i;
        src = X + (size_t)row * DD;
        dh = Xh + (size_t)row * DD;
        dl = Xl + (size_t)row * DD;
    } else {
        row = i - NN;
        if (row >= MM) return;
        src = C + (size_t)row * DD;
        dh = Ch + (size_t)row * DD;
        dl = Cl + (size_t)row * DD;
    }
    const float scale = isX ? LA : 1.0f;

    float s2 = 0.f;
#pragma unroll
    for (int q = 0; q < DD / 8; ++q) {
        float4 a = ((const float4*)src)[2 * q];
        float4 b = ((const float4*)src)[2 * q + 1];
        float vv[8] = {a.x, a.y, a.z, a.w, b.x, b.y, b.z, b.w};
        short8 hv, lv;
#pragma unroll
        for (int e = 0; e < 8; ++e) {
            float v = vv[e];
            s2 = fmaf(v, v, s2);
            float sv = v * scale;
            unsigned short h = f2bf(sv);
            hv[e] = (short)h;
            lv[e] = (short)f2bf(sv - bf2f(h));
        }
        ((short8*)dh)[q] = hv;
        ((short8*)dl)[q] = lv;
    }
    float b = -0.5f * LA * s2;
    if (isX) Bx[row] = b;
    else     w[row] = alphas[row] * exp2f(b);
}

// ---------------------------------------------------------------------------
// Main: LDS-staged double-bf16 MFMA GEMM fused with exp epilogue.
// Block = 4 waves x 64 rows = 256 rows; grid.y = MS slices of M.
// Per block: stage its [MPER][32] bf16 hi/lo C-slab + w slice into LDS once,
// then jt loop reads B-fragments via ds_read_b128 (deterministic latency).
// Accumulator is seeded with Bx (row-only dependence matches C/D layout), so
// epilogue per element is exp2 + fmac only.
// ---------------------------------------------------------------------------
template <int MS>
__global__ __launch_bounds__(256) void rbf_mfma_lds(
    const unsigned short* __restrict__ Xh, const unsigned short* __restrict__ Xl,
    const unsigned short* __restrict__ Ch, const unsigned short* __restrict__ Cl,
    const float* __restrict__ Bx, const float* __restrict__ w,
    float* __restrict__ part)
{
    constexpr int MPER = MM / MS;
    constexpr int NT = MPER / 16;
    __shared__ unsigned short sCh[MPER * DD];
    __shared__ unsigned short sCl[MPER * DD];
    __shared__ float sw[MPER];

    const int tid = threadIdx.x;
    const int wave = tid >> 6;
    const int lane = tid & 63;
    const int l15 = lane & 15;
    const int lhi = lane >> 4;
    const int rowbase = (blockIdx.x * WAVES + wave) * (16 * ROWTILES);
    const int slice = blockIdx.y;
    const int j0 = slice * MPER;

    // ---- stage C slice (hi+lo) and w slice into LDS, vectorized & linear ----
    {
        const float4* gh = (const float4*)(Ch + (size_t)j0 * DD);
        const float4* gl = (const float4*)(Cl + (size_t)j0 * DD);
        float4* lh = (float4*)sCh;
        float4* ll = (float4*)sCl;
        constexpr int NV = MPER * DD / 8;  // 16B chunks per slab
#pragma unroll
        for (int o = tid; o < NV; o += 256) {
            lh[o] = gh[o];
            ll[o] = gl[o];
        }
        for (int o = tid; o < MPER; o += 256) sw[o] = w[j0 + o];
    }

    // ---- A fragments (hi/lo) + Bx seeds, loaded while staging is in flight --
    short8 ah[ROWTILES], al[ROWTILES];
#pragma unroll
    for (int t = 0; t < ROWTILES; ++t) {
        int r = rowbase + t * 16 + l15;
        ah[t] = *(const short8*)(Xh + (size_t)r * DD + lhi * 8);
        al[t] = *(const short8*)(Xl + (size_t)r * DD + lhi * 8);
    }
    f32x4 bx[ROWTILES];
#pragma unroll
    for (int t = 0; t < ROWTILES; ++t) {
        float4 v = *(const float4*)&Bx[rowbase + t * 16 + lhi * 4];
        bx[t][0] = v.x; bx[t][1] = v.y; bx[t][2] = v.z; bx[t][3] = v.w;
    }

    f32x4 acc[ROWTILES];
#pragma unroll
    for (int t = 0; t < ROWTILES; ++t) acc[t] = (f32x4){0.f, 0.f, 0.f, 0.f};

    __syncthreads();

    // ---- main loop: B-fragments from LDS, 3-MFMA double-bf16, fused exp ----
#pragma unroll 2
    for (int jt = 0; jt < NT; ++jt) {
        const int r = jt * 16 + l15;
        short8 bh = *(const short8*)&sCh[r * DD + lhi * 8];
        short8 bl = *(const short8*)&sCl[r * DD + lhi * 8];
        float wj = sw[r];
#pragma unroll
        for (int t = 0; t < ROWTILES; ++t) {
            f32x4 d = bx[t];
            d = __builtin_amdgcn_mfma_f32_16x16x32_bf16(ah[t], bl, d, 0, 0, 0);
            d = __builtin_amdgcn_mfma_f32_16x16x32_bf16(al[t], bh, d, 0, 0, 0);
            d = __builtin_amdgcn_mfma_f32_16x16x32_bf16(ah[t], bh, d, 0, 0, 0);
#pragma unroll
            for (int rr = 0; rr < 4; ++rr)
                acc[t][rr] = fmaf(wj, __builtin_amdgcn_exp2f(d[rr]), acc[t][rr]);
        }
    }

    // ---- reduce over the 16 columns (lane bits 0..3), store float4 ----------
#pragma unroll
    for (int t = 0; t < ROWTILES; ++t)
#pragma unroll
        for (int rr = 0; rr < 4; ++rr) {
            float v = acc[t][rr];
            v += __shfl_xor(v, 1, 64);
            v += __shfl_xor(v, 2, 64);
            v += __shfl_xor(v, 4, 64);
            v += __shfl_xor(v, 8, 64);
            acc[t][rr] = v;
        }
    if (l15 == 0) {
#pragma unroll
        for (int t = 0; t < ROWTILES; ++t)
            *(f32x4*)&part[(size_t)slice * NN + rowbase + t * 16 + lhi * 4] = acc[t];
    }
}

template <int MS>
__global__ __launch_bounds__(256) void reduce_kern(const float* __restrict__ part,
                                                   float* __restrict__ out) {
    int i = blockIdx.x * 256 + threadIdx.x;
    float s = 0.f;
#pragma unroll
    for (int k = 0; k < MS; ++k) s += part[(size_t)k * NN + i];
    out[i] = s;
}

// ---------------------------------------------------------------------------
// Fallback (round-1 VALU path) in case ws_size is too small.
// ---------------------------------------------------------------------------
__global__ __launch_bounds__(256) void wkern(const float* __restrict__ C,
                                             const float* __restrict__ alphas,
                                             const float* __restrict__ sigma,
                                             float* __restrict__ w) {
    int j = blockIdx.x * 256 + threadIdx.x;
    if (j >= MM) return;
    float g = sigma[0];
    float inv_g2 = 1.0f / (g * g);
    const float4* cp = (const float4*)(C + (size_t)j * DD);
    float y2 = 0.f;
#pragma unroll
    for (int q = 0; q < DD / 4; ++q) {
        float4 v = cp[q];
        y2 = fmaf(v.x, v.x, y2);
        y2 = fmaf(v.y, v.y, y2);
        y2 = fmaf(v.z, v.z, y2);
        y2 = fmaf(v.w, v.w, y2);
    }
    w[j] = alphas[j] * exp2f(-0.5f * inv_g2 * 1.44269504088896340736f * y2);
}

__global__ __launch_bounds__(128) void rbf_valu(const float* __restrict__ X,
                                                const float* __restrict__ C,
                                                const float* __restrict__ w,
                                                const float* __restrict__ sigma,
                                                float* __restrict__ out) {
    const int row = blockIdx.x * 128 + threadIdx.x;
    const float g = sigma[0];
    const float A = 1.44269504088896340736f / (g * g);
    float x[DD];
    const float4* xp = (const float4*)(X + (size_t)row * DD);
#pragma unroll
    for (int q = 0; q < DD / 4; ++q) {
        float4 v = xp[q];
        x[4 * q + 0] = v.x; x[4 * q + 1] = v.y;
        x[4 * q + 2] = v.z; x[4 * q + 3] = v.w;
    }
    float x2 = 0.f;
#pragma unroll
    for (int d = 0; d < DD; ++d) x2 = fmaf(x[d], x[d], x2);
    const float B = -0.5f * A * x2;
    float acc = 0.f;
#pragma unroll 2
    for (int j = 0; j < MM; ++j) {
        const float* cj = C + (size_t)j * DD;
        float d0 = 0.f, d1 = 0.f, d2 = 0.f, d3 = 0.f;
#pragma unroll
        for (int d = 0; d < DD; d += 4) {
            d0 = fmaf(cj[d + 0], x[d + 0], d0);
            d1 = fmaf(cj[d + 1], x[d + 1], d1);
            d2 = fmaf(cj[d + 2], x[d + 2], d2);
            d3 = fmaf(cj[d + 3], x[d + 3], d3);
        }
        float dot = (d0 + d1) + (d2 + d3);
        acc = fmaf(w[j], exp2f(fmaf(dot, A, B)), acc);
    }
    out[row] = acc;
}

extern "C" void kernel_launch(void* const* d_in, const int* in_sizes, int n_in,
                              void* d_out, int out_size, void* d_ws, size_t ws_size,
                              hipStream_t stream) {
    const float* X  = (const float*)d_in[0];
    const float* C  = (const float*)d_in[1];
    const float* al = (const float*)d_in[2];
    const float* sg = (const float*)d_in[3];
    float* out = (float*)d_out;

    // Workspace layout (all 16B aligned).
    size_t off = 0;
    unsigned short* Xh = (unsigned short*)((char*)d_ws + off); off += (size_t)NN * DD * 2;
    unsigned short* Xl = (unsigned short*)((char*)d_ws + off); off += (size_t)NN * DD * 2;
    unsigned short* Ch = (unsigned short*)((char*)d_ws + off); off += (size_t)MM * DD * 2;
    unsigned short* Cl = (unsigned short*)((char*)d_ws + off); off += (size_t)MM * DD * 2;
    float* Bx = (float*)((char*)d_ws + off); off += (size_t)NN * 4;
    float* w  = (float*)((char*)d_ws + off); off += (size_t)MM * 4;
    float* part = (float*)((char*)d_ws + off);
    const size_t base = off;

    const size_t need16 = base + (size_t)16 * NN * 4;
    const size_t need8  = base + (size_t)8 * NN * 4;

    if (ws_size >= need8) {
        prep_kern<<<(NN + MM) / 256, 256, 0, stream>>>(X, C, al, sg, Xh, Xl, Ch, Cl, Bx, w);
        if (ws_size >= need16) {
            dim3 grid(NN / (WAVES * 16 * ROWTILES), 16);
            rbf_mfma_lds<16><<<grid, 64 * WAVES, 0, stream>>>(Xh, Xl, Ch, Cl, Bx, w, part);
            reduce_kern<16><<<NN / 256, 256, 0, stream>>>(part, out);
        } else {
            dim3 grid(NN / (WAVES * 16 * ROWTILES), 8);
            rbf_mfma_lds<8><<<grid, 64 * WAVES, 0, stream>>>(Xh, Xl, Ch, Cl, Bx, w, part);
            reduce_kern<8><<<NN / 256, 256, 0, stream>>>(part, out);
        }
    } else {
        // Fallback: fp32 VALU path, needs only 16 KB for w.
        float* wf = (float*)d_ws;
        wkern<<<MM / 256, 256, 0, stream>>>(C, al, sg, wf);
        rbf_valu<<<NN / 128, 128, 0, stream>>>(X, C, wf, sg, out);
    }
}